// Round 2
// baseline (110.323 us; speedup 1.0000x reference)
//
#include <hip/hip_runtime.h>
#include <math.h>

#define KMAX  64
#define HSZ   256
#define EMPTY 0xFFFFFFFFu
#define SENT  0xFFFFFFFFu
#define NB1   32          // pass1 blocks per batch
#define PX    8           // pixels per thread per tile in pass2
#define LAM   300.0f

struct Part {             // per pass1 block partial segment sums
    unsigned keys[KMAX];  // SENT-padded
    unsigned cnt[KMAX];
    float s0[KMAX], s1[KMAX], s2[KMAX];
};

struct Ctrl {
    unsigned tk[16];      // tk[b]: per-batch pass2 tickets; tk[15]: final ticket
    float batch_loss[8];
};

__device__ __forceinline__ unsigned key_of(float t0, float t1, float t2) {
    return ((unsigned)t0 << 16) | ((unsigned)t1 << 8) | (unsigned)t2;
}

__device__ __forceinline__ int lower_bound64(const unsigned* su, unsigned key) {
    int lo = 0;
    if (su[lo + 31] < key) lo += 32;
    if (su[lo + 15] < key) lo += 16;
    if (su[lo + 7]  < key) lo += 8;
    if (su[lo + 3]  < key) lo += 4;
    if (su[lo + 1]  < key) lo += 2;
    if (su[lo]      < key) lo += 1;
    return lo;
}

__device__ __forceinline__ float huber1(float e) {
    float a = fabsf(e);
    return a < 1.0f ? 0.5f * e * e : a - 0.5f;
}

// ---------------- pass 1: block-local dedup + partial segment sums ----------
__global__ __launch_bounds__(256) void k_pass1(const float* __restrict__ pred,
        const float* __restrict__ tgt, Part* __restrict__ parts,
        Ctrl* ctrl, int P, int nb1)
{
    int b = blockIdx.y, bx = blockIdx.x, tid = threadIdx.x;
    const float* tg = tgt + (size_t)b * 3 * P;
    const float* pr = pred + (size_t)b * 3 * P;

    __shared__ unsigned hkey[HSZ];
    __shared__ int      hslot[HSZ];
    __shared__ unsigned skey[KMAX];
    __shared__ unsigned scnt[KMAX];
    __shared__ float ss0[KMAX], ss1[KMAX], ss2[KMAX];
    __shared__ unsigned M;

    hkey[tid] = EMPTY;
    if (tid < KMAX) { skey[tid] = SENT; scnt[tid] = 0u; ss0[tid] = 0.f; ss1[tid] = 0.f; ss2[tid] = 0.f; }
    if (tid == 0) M = 0u;
    if (b == 0 && bx == 0 && tid < 16) ctrl->tk[tid] = 0u;   // tickets for pass2
    __syncthreads();

    int stride = nb1 * 256;
    // phase 1: insert keys (check-first, CAS on empty)
    for (int p = bx * 256 + tid; p < P; p += stride) {
        unsigned key = key_of(tg[p], tg[p + P], tg[p + 2 * P]);
        unsigned s = (key * 2654435761u) >> 24;
        while (true) {
            unsigned cur = *(volatile unsigned*)&hkey[s];
            if (cur == key) break;
            if (cur == EMPTY) {
                unsigned old = atomicCAS(&hkey[s], EMPTY, key);
                if (old == EMPTY || old == key) break;
            } else {
                s = (s + 1) & (HSZ - 1);
            }
        }
    }
    __syncthreads();
    // compact: hash entry -> local slot
    {
        unsigned k = hkey[tid];
        if (k != EMPTY) {
            unsigned pos = atomicAdd(&M, 1u);
            if (pos < KMAX) { skey[pos] = k; hslot[tid] = (int)pos; }
        }
    }
    __syncthreads();
    // phase 2: accumulate per local slot
    for (int p = bx * 256 + tid; p < P; p += stride) {
        unsigned key = key_of(tg[p], tg[p + P], tg[p + 2 * P]);
        unsigned s = (key * 2654435761u) >> 24;
        while (hkey[s] != key) s = (s + 1) & (HSZ - 1);
        int ls = hslot[s];
        atomicAdd(&scnt[ls], 1u);
        atomicAdd(&ss0[ls], pr[p]);
        atomicAdd(&ss1[ls], pr[p + P]);
        atomicAdd(&ss2[ls], pr[p + 2 * P]);
    }
    __syncthreads();
    if (tid < KMAX) {
        Part* pt = &parts[(size_t)b * nb1 + bx];
        pt->keys[tid] = skey[tid];
        pt->cnt[tid]  = scnt[tid];
        pt->s0[tid] = ss0[tid];
        pt->s1[tid] = ss1[tid];
        pt->s2[tid] = ss2[tid];
    }
}

// ------------- pass 2: merge partials, derive, P x K loop, finalize ---------
__global__ __launch_bounds__(256) void k_pass2(const float* __restrict__ pred,
        const float* __restrict__ tgt, const Part* __restrict__ parts,
        float* __restrict__ partial2, Ctrl* ctrl,
        const unsigned char* __restrict__ no_bg,
        float* __restrict__ out, int P, int B, int nb1, int nb2)
{
    int b = blockIdx.y, bx = blockIdx.x, tid = threadIdx.x;
    const float* tg = tgt + (size_t)b * 3 * P;
    const float* pr = pred + (size_t)b * 3 * P;

    __shared__ unsigned hkey[HSZ];
    __shared__ unsigned lkey[KMAX];
    __shared__ unsigned su[KMAX];
    __shared__ unsigned Mctr;
    __shared__ unsigned dcnt[KMAX];
    __shared__ float gs0[KMAX], gs1[KMAX], gs2[KMAX];
    __shared__ float4 smv[KMAX];   // {m0, m1, m2, LAM * a_k}
    __shared__ float4 srv[KMAX];   // {ref0, ref1, ref2 (bg-zeroed means), w_h}
    __shared__ int scnted[KMAX];
    __shared__ int sct;
    __shared__ int sM;

    hkey[tid] = EMPTY;
    if (tid < KMAX) {
        lkey[tid] = SENT; su[tid] = SENT; dcnt[tid] = 0u;
        gs0[tid] = 0.f; gs1[tid] = 0.f; gs2[tid] = 0.f;
    }
    if (tid == 0) Mctr = 0u;
    __syncthreads();

    int total = nb1 * KMAX;
    // A: dedup all partial keys
    for (int i = tid; i < total; i += 256) {
        unsigned key = parts[(size_t)b * nb1 + (i >> 6)].keys[i & 63];
        if (key == SENT) continue;
        unsigned s = (key * 2654435761u) >> 24;
        while (true) {
            unsigned cur = *(volatile unsigned*)&hkey[s];
            if (cur == key) break;
            if (cur == EMPTY) {
                unsigned old = atomicCAS(&hkey[s], EMPTY, key);
                if (old == EMPTY || old == key) break;
            } else {
                s = (s + 1) & (HSZ - 1);
            }
        }
    }
    __syncthreads();
    // B: compact
    {
        unsigned k = hkey[tid];
        if (k != EMPTY) {
            unsigned pos = atomicAdd(&Mctr, 1u);
            if (pos < KMAX) lkey[pos] = k;
        }
    }
    __syncthreads();
    int M = (int)Mctr; if (M > KMAX) M = KMAX;
    // C: rank sort (keys distinct)
    if (tid < M) {
        unsigned key = lkey[tid];
        int rank = 0;
        for (int j = 0; j < M; ++j) rank += (lkey[j] < key) ? 1 : 0;
        su[rank] = key;
    }
    if (tid == 0) sM = M;
    __syncthreads();
    // D: accumulate partials into global segments
    for (int i = tid; i < total; i += 256) {
        const Part* pt = &parts[(size_t)b * nb1 + (i >> 6)];
        unsigned key = pt->keys[i & 63];
        if (key == SENT) continue;
        int g = lower_bound64(su, key);
        atomicAdd(&dcnt[g], pt->cnt[i & 63]);
        atomicAdd(&gs0[g], pt->s0[i & 63]);
        atomicAdd(&gs1[g], pt->s1[i & 63]);
        atomicAdd(&gs2[g], pt->s2[i & 63]);
    }
    __syncthreads();
    // E: derive per-segment constants (wave 0)
    if (tid < KMAX) {
        unsigned c = dcnt[tid];
        bool valid = c > 0u;
        float n = valid ? (float)c : 1.0f;
        float inv_n = 1.0f / n;
        float m0 = gs0[tid] * inv_n, m1 = gs1[tid] * inv_n, m2 = gs2[tid] * inv_n;
        bool isbg = valid && (su[tid] == 0u);
        bool nb = no_bg[b] != 0;
        bool counted = valid && (!isbg || !nb);
        long n_out = (long)P - (long)c;
        bool active = valid && !isbg && (n_out > 0);
        float noutf = (n_out > 0) ? (float)n_out : 1.0f;
        float saw = active ? (LAM * 10.0f / sqrtf(n) / noutf) : 0.0f;
        float whw = counted ? (1.0f / (3.0f * n)) : 0.0f;
        smv[tid] = make_float4(m0, m1, m2, saw);
        srv[tid] = make_float4(isbg ? 0.f : m0, isbg ? 0.f : m1, isbg ? 0.f : m2, whw);
        scnted[tid] = counted ? 1 : 0;
        unsigned long long msk = __ballot(counted);
        if (tid == 0) sct = (int)__popcll(msk);
    }
    __syncthreads();

    // F: main P x K loop, PX pixels per thread in registers
    float acc = 0.0f;
    const int M2 = sM;
    for (long tile = bx; tile * (256L * PX) < (long)P; tile += nb2) {
        int base = (int)(tile * (256 * PX)) + tid;
        float q0[PX], q1[PX], q2[PX], fa[PX];
        int sid[PX];
        #pragma unroll
        for (int j = 0; j < PX; ++j) {
            int p = base + j * 256;
            bool v = p < P;
            int pc = v ? p : 0;
            float t0 = tg[pc], t1 = tg[pc + P], t2 = tg[pc + 2 * P];
            unsigned key = key_of(t0, t1, t2);
            int lo = lower_bound64(su, key);
            sid[j] = lo;
            q0[j] = pr[pc]; q1[j] = pr[pc + P]; q2[j] = pr[pc + 2 * P];
            fa[j] = 0.f;
            float4 rv = srv[lo];
            float h = huber1(q0[j] - rv.x) + huber1(q1[j] - rv.y) + huber1(q2[j] - rv.z);
            acc += v ? rv.w * h : 0.0f;
        }
        for (int k = 0; k < M2; ++k) {
            float4 v = smv[k];
            #pragma unroll
            for (int j = 0; j < PX; ++j) {
                float e0 = q0[j] - v.x, e1 = q1[j] - v.y, e2 = q2[j] - v.z;
                float d = e0 * e0 + e1 * e1 + e2 * e2;
                float r = __builtin_amdgcn_rcpf(1.0f + d);
                fa[j] = fmaf(v.w, r, fa[j]);
            }
        }
        #pragma unroll
        for (int j = 0; j < PX; ++j) {
            int p = base + j * 256;
            bool v = p < P;
            float4 vv = smv[sid[j]];
            float e0 = q0[j] - vv.x, e1 = q1[j] - vv.y, e2 = q2[j] - vv.z;
            float d = e0 * e0 + e1 * e1 + e2 * e2;
            float r = __builtin_amdgcn_rcpf(1.0f + d);
            float t = fa[j] - vv.w * r;      // exclude own-segment term
            acc += v ? t : 0.0f;
        }
    }

    // G: block reduce
    #pragma unroll
    for (int o = 32; o > 0; o >>= 1) acc += __shfl_xor(acc, o);
    __shared__ float wred[4];
    int lane = tid & 63, wid = tid >> 6;
    if (lane == 0) wred[wid] = acc;
    __syncthreads();
    __shared__ int amLast;
    if (tid == 0) {
        float tot = wred[0] + wred[1] + wred[2] + wred[3];
        __hip_atomic_store(&partial2[(size_t)b * nb2 + bx], tot,
                           __ATOMIC_RELEASE, __HIP_MEMORY_SCOPE_AGENT);
        __threadfence();
        unsigned old = atomicAdd(&ctrl->tk[b], 1u);
        amLast = (old == (unsigned)(nb2 - 1)) ? 1 : 0;
    }
    __syncthreads();
    if (!amLast) return;

    // H: last block of this batch — deterministic reduce + pairwise + combine
    __threadfence();
    __shared__ double dred[256];
    double dv = 0.0;
    if (tid < nb2)
        dv = (double)__hip_atomic_load(&partial2[(size_t)b * nb2 + tid],
                                       __ATOMIC_ACQUIRE, __HIP_MEMORY_SCOPE_AGENT);
    dred[tid] = dv;
    __syncthreads();
    for (int s = 128; s > 0; s >>= 1) {
        if (tid < s) dred[tid] += dred[tid + s];
        __syncthreads();
    }

    float rs = 0.f;
    if (tid < KMAX && scnted[tid]) {
        float4 a = srv[tid];
        for (int j = 0; j < KMAX; ++j) {
            if (j == tid || !scnted[j]) continue;
            float4 c2 = srv[j];
            float d0 = a.x - c2.x, d1 = a.y - c2.y, d2 = a.z - c2.z;
            rs += LAM / (d0 * d0 + d1 * d1 + d2 * d2 + 1.0f);
        }
    }
    #pragma unroll
    for (int o = 32; o > 0; o >>= 1) rs += __shfl_xor(rs, o);

    if (tid == 0) {
        int ct = sct;
        float ctf = (float)ct;
        float npairs = ctf * (ctf - 1.0f) * 0.5f;
        float mean_sep = (ct > 1) ? (rs * 0.5f / fmaxf(npairs, 1.0f)) : 0.0f;
        float loss = ((float)dred[0] + mean_sep) / fmaxf(ctf, 1.0f);
        __hip_atomic_store(&ctrl->batch_loss[b], loss,
                           __ATOMIC_RELEASE, __HIP_MEMORY_SCOPE_AGENT);
        __threadfence();
        unsigned old2 = atomicAdd(&ctrl->tk[15], 1u);
        if (old2 == (unsigned)(B - 1)) {
            __threadfence();
            float s = 0.f;
            for (int i = 0; i < B; ++i)
                s += __hip_atomic_load(&ctrl->batch_loss[i],
                                       __ATOMIC_ACQUIRE, __HIP_MEMORY_SCOPE_AGENT);
            out[0] = s / (float)B;
        }
    }
}

extern "C" void kernel_launch(void* const* d_in, const int* in_sizes, int n_in,
                              void* d_out, int out_size, void* d_ws, size_t ws_size,
                              hipStream_t stream) {
    const float* pred = (const float*)d_in[0];
    const float* tgt  = (const float*)d_in[1];
    const unsigned char* nb = (const unsigned char*)d_in[2];
    float* out = (float*)d_out;

    int B = in_sizes[2];
    int P = in_sizes[0] / (3 * B);
    int nb2 = (P + 256 * PX - 1) / (256 * PX);
    if (nb2 > 256) nb2 = 256;

    char* wsb = (char*)d_ws;
    Part* parts = (Part*)wsb;
    size_t partsBytes = (size_t)B * NB1 * sizeof(Part);
    float* partial2 = (float*)(wsb + ((partsBytes + 255) & ~(size_t)255));
    size_t p2Bytes = (size_t)B * 256 * sizeof(float);
    Ctrl* ctrl = (Ctrl*)((char*)partial2 + ((p2Bytes + 255) & ~(size_t)255));

    k_pass1<<<dim3(NB1, B), 256, 0, stream>>>(pred, tgt, parts, ctrl, P, NB1);
    k_pass2<<<dim3(nb2, B), 256, 0, stream>>>(pred, tgt, parts, partial2, ctrl,
                                              nb, out, P, B, NB1, nb2);
}

// Round 3
// 83.209 us; speedup vs baseline: 1.3259x; 1.3259x over previous
//
#include <hip/hip_runtime.h>
#include <math.h>

#define KMAX 64
#define HSZ  256
#define EMPTY 0xFFFFFFFFu
#define SENT  0xFFFFFFFFu
#define LAM  300.0f
#define MAXNB1 128
#define MAXNB2 256

struct Acc {
    unsigned uniq[KMAX];
    unsigned cnt[KMAX];
    float s0[KMAX], s1[KMAX], s2[KMAX];
};
struct Ctrl {
    unsigned tk[16];       // tk[b]: k_main per-batch tickets; tk[15]: final
    float batch_loss[8];
};

__device__ __forceinline__ unsigned key_of(float r, float g, float b) {
    return ((unsigned)r << 16) | ((unsigned)g << 8) | (unsigned)b;
}

__device__ __forceinline__ void hash_insert(unsigned* hkey, unsigned key) {
    unsigned s = (key * 2654435761u) >> 24;
    for (int probe = 0; probe < HSZ; ++probe) {
        unsigned cur = *(volatile unsigned*)&hkey[s];
        if (cur == key) return;
        if (cur == EMPTY) {
            unsigned old = atomicCAS(&hkey[s], EMPTY, key);
            if (old == EMPTY || old == key) return;
        } else {
            s = (s + 1) & (HSZ - 1);
        }
    }
}

__device__ __forceinline__ int lower_bound64(const unsigned* su, unsigned key) {
    int lo = 0;
    if (su[lo + 31] < key) lo += 32;
    if (su[lo + 15] < key) lo += 16;
    if (su[lo + 7]  < key) lo += 8;
    if (su[lo + 3]  < key) lo += 4;
    if (su[lo + 1]  < key) lo += 2;
    if (su[lo]      < key) lo += 1;
    return lo;
}

__device__ __forceinline__ float huber1(float e) {
    float a = fabsf(e);
    return a < 1.0f ? 0.5f * e * e : a - 0.5f;
}

// K1: per-block dedup of target colors -> compact key list per block
__global__ __launch_bounds__(256) void k_dedup(const float* __restrict__ tgt,
        unsigned* __restrict__ pkeys, int P, int nb1)
{
    int b = blockIdx.y, bx = blockIdx.x, tid = threadIdx.x;
    const float* tg = tgt + (size_t)b * 3 * P;
    __shared__ unsigned hkey[HSZ];
    __shared__ unsigned skey[KMAX];
    __shared__ unsigned cc;
    hkey[tid] = EMPTY;
    if (tid < KMAX) skey[tid] = SENT;
    if (tid == 0) cc = 0;
    __syncthreads();

    int ngrp = P >> 2;
    for (int g = bx * 256 + tid; g < ngrp; g += nb1 * 256) {
        float4 r  = *(const float4*)(tg + 4 * (size_t)g);
        float4 gg = *(const float4*)(tg + P + 4 * (size_t)g);
        float4 bb = *(const float4*)(tg + 2 * P + 4 * (size_t)g);
        hash_insert(hkey, key_of(r.x, gg.x, bb.x));
        hash_insert(hkey, key_of(r.y, gg.y, bb.y));
        hash_insert(hkey, key_of(r.z, gg.z, bb.z));
        hash_insert(hkey, key_of(r.w, gg.w, bb.w));
    }
    __syncthreads();
    unsigned k = hkey[tid];
    if (k != EMPTY) {
        unsigned pos = atomicAdd(&cc, 1u);
        if (pos < KMAX) skey[pos] = k;
    }
    __syncthreads();
    if (tid < KMAX) pkeys[((size_t)b * nb1 + bx) * KMAX + tid] = skey[tid];
}

// K2: merge block key lists -> sorted uniq; zero accumulators and tickets
__global__ __launch_bounds__(256) void k_merge(const unsigned* __restrict__ pkeys,
        Acc* __restrict__ acc, Ctrl* __restrict__ ctrl, int nb1)
{
    int b = blockIdx.x, tid = threadIdx.x;
    __shared__ unsigned hkey[HSZ];
    __shared__ unsigned lkey[KMAX];
    __shared__ unsigned su[KMAX];
    __shared__ unsigned cc;
    hkey[tid] = EMPTY;
    if (tid < KMAX) { lkey[tid] = SENT; su[tid] = SENT; }
    if (tid == 0) cc = 0;
    __syncthreads();

    int total = nb1 * KMAX;
    for (int i = tid; i < total; i += 256) {
        unsigned key = pkeys[(size_t)b * total + i];
        if (key != SENT) hash_insert(hkey, key);
    }
    __syncthreads();
    unsigned k = hkey[tid];
    if (k != EMPTY) {
        unsigned pos = atomicAdd(&cc, 1u);
        if (pos < KMAX) lkey[pos] = k;
    }
    __syncthreads();
    int M = (int)cc; if (M > KMAX) M = KMAX;
    if (tid < M) {
        unsigned key = lkey[tid];
        int rank = 0;
        for (int j = 0; j < M; ++j) rank += (lkey[j] < key) ? 1 : 0;
        su[rank] = key;
    }
    __syncthreads();
    if (tid < KMAX) {
        Acc* a = &acc[b];
        a->uniq[tid] = su[tid];
        a->cnt[tid] = 0u;
        a->s0[tid] = 0.f; a->s1[tid] = 0.f; a->s2[tid] = 0.f;
    }
    if (tid == 0) {
        ctrl->tk[b] = 0u;
        if (b == 0) ctrl->tk[15] = 0u;
    }
}

// K3: segment counts & pred sums (shared pre-aggregation, global atomic flush)
__global__ __launch_bounds__(256) void k_accum(const float* __restrict__ pred,
        const float* __restrict__ tgt, Acc* __restrict__ acc, int P, int nb2)
{
    int b = blockIdx.y, bx = blockIdx.x, tid = threadIdx.x;
    const float* tg = tgt + (size_t)b * 3 * P;
    const float* pr = pred + (size_t)b * 3 * P;
    __shared__ unsigned su[KMAX];
    __shared__ unsigned scnt[KMAX];
    __shared__ float ss0[KMAX], ss1[KMAX], ss2[KMAX];
    if (tid < KMAX) {
        su[tid] = acc[b].uniq[tid];
        scnt[tid] = 0u; ss0[tid] = 0.f; ss1[tid] = 0.f; ss2[tid] = 0.f;
    }
    __syncthreads();

    int ngrp = P >> 2;
    for (int g = bx * 256 + tid; g < ngrp; g += nb2 * 256) {
        float4 tr = *(const float4*)(tg + 4 * (size_t)g);
        float4 tc = *(const float4*)(tg + P + 4 * (size_t)g);
        float4 tb = *(const float4*)(tg + 2 * P + 4 * (size_t)g);
        float4 pa = *(const float4*)(pr + 4 * (size_t)g);
        float4 pb = *(const float4*)(pr + P + 4 * (size_t)g);
        float4 pc = *(const float4*)(pr + 2 * P + 4 * (size_t)g);
        float t0[4] = {tr.x, tr.y, tr.z, tr.w};
        float t1[4] = {tc.x, tc.y, tc.z, tc.w};
        float t2[4] = {tb.x, tb.y, tb.z, tb.w};
        float q0[4] = {pa.x, pa.y, pa.z, pa.w};
        float q1[4] = {pb.x, pb.y, pb.z, pb.w};
        float q2[4] = {pc.x, pc.y, pc.z, pc.w};
        #pragma unroll
        for (int j = 0; j < 4; ++j) {
            int ls = lower_bound64(su, key_of(t0[j], t1[j], t2[j]));
            atomicAdd(&scnt[ls], 1u);
            atomicAdd(&ss0[ls], q0[j]);
            atomicAdd(&ss1[ls], q1[j]);
            atomicAdd(&ss2[ls], q2[j]);
        }
    }
    __syncthreads();
    if (tid < KMAX && scnt[tid] > 0u) {
        atomicAdd(&acc[b].cnt[tid], scnt[tid]);
        atomicAdd(&acc[b].s0[tid], ss0[tid]);
        atomicAdd(&acc[b].s1[tid], ss1[tid]);
        atomicAdd(&acc[b].s2[tid], ss2[tid]);
    }
}

// K4: derive per-segment constants, P x K main loop, last-block finalize
__global__ __launch_bounds__(256) void k_main(const float* __restrict__ pred,
        const float* __restrict__ tgt, const Acc* __restrict__ acc,
        float* __restrict__ partial2, Ctrl* __restrict__ ctrl,
        const unsigned char* __restrict__ no_bg, float* __restrict__ out,
        int P, int B, int nb2)
{
    int b = blockIdx.y, bx = blockIdx.x, tid = threadIdx.x;
    const float* tg = tgt + (size_t)b * 3 * P;
    const float* pr = pred + (size_t)b * 3 * P;

    __shared__ unsigned su[KMAX];
    __shared__ float4 smv[KMAX];   // {m0,m1,m2, LAM*a_k}
    __shared__ float4 srv[KMAX];   // {bg-zeroed means, w_h}
    __shared__ int scnted[KMAX];
    __shared__ int sct, sM;

    if (tid < KMAX) {
        const Acc* a = &acc[b];
        unsigned key = a->uniq[tid];
        unsigned c = a->cnt[tid];
        su[tid] = key;
        bool valid = key != SENT;
        float n = (c > 0u) ? (float)c : 1.0f;
        float inv_n = 1.0f / n;
        float m0 = a->s0[tid] * inv_n, m1 = a->s1[tid] * inv_n, m2 = a->s2[tid] * inv_n;
        bool isbg = valid && (key == 0u);
        bool nb = no_bg[b] != 0;
        bool counted = valid && (!isbg || !nb);
        long n_out = (long)P - (long)c;
        bool active = valid && !isbg && (n_out > 0);
        float noutf = (n_out > 0) ? (float)n_out : 1.0f;
        float saw = active ? (LAM * 10.0f / (sqrtf(n) * noutf)) : 0.0f;
        float whw = counted ? (1.0f / (3.0f * n)) : 0.0f;
        smv[tid] = make_float4(m0, m1, m2, saw);
        srv[tid] = make_float4(isbg ? 0.f : m0, isbg ? 0.f : m1, isbg ? 0.f : m2, whw);
        scnted[tid] = counted ? 1 : 0;
        unsigned long long mc = __ballot(counted);
        unsigned long long mv = __ballot(valid);
        if (tid == 0) { sct = (int)__popcll(mc); sM = (int)__popcll(mv); }
    }
    __syncthreads();

    float accs = 0.f;
    const int M2 = sM;
    int ngrp = P >> 2;
    for (int g = bx * 256 + tid; g < ngrp; g += nb2 * 256) {
        float4 tr = *(const float4*)(tg + 4 * (size_t)g);
        float4 tc = *(const float4*)(tg + P + 4 * (size_t)g);
        float4 tb = *(const float4*)(tg + 2 * P + 4 * (size_t)g);
        float4 pa = *(const float4*)(pr + 4 * (size_t)g);
        float4 pb = *(const float4*)(pr + P + 4 * (size_t)g);
        float4 pc = *(const float4*)(pr + 2 * P + 4 * (size_t)g);
        float t0[4] = {tr.x, tr.y, tr.z, tr.w};
        float t1[4] = {tc.x, tc.y, tc.z, tc.w};
        float t2[4] = {tb.x, tb.y, tb.z, tb.w};
        float q0[4] = {pa.x, pa.y, pa.z, pa.w};
        float q1[4] = {pb.x, pb.y, pb.z, pb.w};
        float q2[4] = {pc.x, pc.y, pc.z, pc.w};
        int sid[4]; float fa[4];
        #pragma unroll
        for (int j = 0; j < 4; ++j) {
            int lo = lower_bound64(su, key_of(t0[j], t1[j], t2[j]));
            sid[j] = lo;
            float4 rv = srv[lo];
            accs += rv.w * (huber1(q0[j] - rv.x) + huber1(q1[j] - rv.y)
                            + huber1(q2[j] - rv.z));
            fa[j] = 0.f;
        }
        for (int k = 0; k < M2; ++k) {
            float4 v = smv[k];
            #pragma unroll
            for (int j = 0; j < 4; ++j) {
                float e0 = q0[j] - v.x, e1 = q1[j] - v.y, e2 = q2[j] - v.z;
                float d = fmaf(e0, e0, fmaf(e1, e1, e2 * e2));
                fa[j] = fmaf(v.w, __builtin_amdgcn_rcpf(1.0f + d), fa[j]);
            }
        }
        #pragma unroll
        for (int j = 0; j < 4; ++j) {
            float4 v = smv[sid[j]];
            float e0 = q0[j] - v.x, e1 = q1[j] - v.y, e2 = q2[j] - v.z;
            float d = fmaf(e0, e0, fmaf(e1, e1, e2 * e2));
            accs += fa[j] - v.w * __builtin_amdgcn_rcpf(1.0f + d);
        }
    }

    // block reduce
    #pragma unroll
    for (int o = 32; o > 0; o >>= 1) accs += __shfl_xor(accs, o);
    __shared__ float wred[4];
    int lane = tid & 63, wid = tid >> 6;
    if (lane == 0) wred[wid] = accs;
    __syncthreads();
    __shared__ int amLast;
    if (tid == 0) {
        float tot = wred[0] + wred[1] + wred[2] + wred[3];
        __hip_atomic_store(&partial2[(size_t)b * nb2 + bx], tot,
                           __ATOMIC_RELEASE, __HIP_MEMORY_SCOPE_AGENT);
        __threadfence();
        unsigned old = atomicAdd(&ctrl->tk[b], 1u);
        amLast = (old == (unsigned)(nb2 - 1)) ? 1 : 0;
    }
    __syncthreads();
    if (!amLast) return;

    // last block of this batch: deterministic reduce + pairwise + combine
    __threadfence();
    __shared__ double dred[256];
    double dv = 0.0;
    if (tid < nb2)
        dv = (double)__hip_atomic_load(&partial2[(size_t)b * nb2 + tid],
                                       __ATOMIC_ACQUIRE, __HIP_MEMORY_SCOPE_AGENT);
    dred[tid] = dv;
    __syncthreads();
    for (int s = 128; s > 0; s >>= 1) {
        if (tid < s) dred[tid] += dred[tid + s];
        __syncthreads();
    }

    float rs = 0.f;
    if (tid < KMAX && scnted[tid]) {
        float4 a = srv[tid];
        for (int j = 0; j < KMAX; ++j) {
            if (j == tid || !scnted[j]) continue;
            float4 c2 = srv[j];
            float d0 = a.x - c2.x, d1 = a.y - c2.y, d2 = a.z - c2.z;
            rs += LAM / (d0 * d0 + d1 * d1 + d2 * d2 + 1.0f);
        }
    }
    #pragma unroll
    for (int o = 32; o > 0; o >>= 1) rs += __shfl_xor(rs, o);

    if (tid == 0) {
        int ct = sct;
        float ctf = (float)ct;
        float npairs = ctf * (ctf - 1.0f) * 0.5f;
        float mean_sep = (ct > 1) ? (rs * 0.5f / fmaxf(npairs, 1.0f)) : 0.0f;
        float loss = ((float)dred[0] + mean_sep) / fmaxf(ctf, 1.0f);
        __hip_atomic_store(&ctrl->batch_loss[b], loss,
                           __ATOMIC_RELEASE, __HIP_MEMORY_SCOPE_AGENT);
        __threadfence();
        unsigned old2 = atomicAdd(&ctrl->tk[15], 1u);
        if (old2 == (unsigned)(B - 1)) {
            __threadfence();
            float s = 0.f;
            for (int i = 0; i < B; ++i)
                s += __hip_atomic_load(&ctrl->batch_loss[i],
                                       __ATOMIC_ACQUIRE, __HIP_MEMORY_SCOPE_AGENT);
            out[0] = s / (float)B;
        }
    }
}

extern "C" void kernel_launch(void* const* d_in, const int* in_sizes, int n_in,
                              void* d_out, int out_size, void* d_ws, size_t ws_size,
                              hipStream_t stream) {
    const float* pred = (const float*)d_in[0];
    const float* tgt  = (const float*)d_in[1];
    const unsigned char* nb = (const unsigned char*)d_in[2];
    float* out = (float*)d_out;

    int B = in_sizes[2];
    int P = in_sizes[0] / (3 * B);
    int ngrp = P >> 2;
    int nb1 = (ngrp + 255) / 256; if (nb1 > MAXNB1) nb1 = MAXNB1;
    int nb2 = (ngrp + 255) / 256; if (nb2 > MAXNB2) nb2 = MAXNB2;

    char* wsb = (char*)d_ws;
    unsigned* pkeys = (unsigned*)wsb;
    size_t pkBytes = (size_t)B * nb1 * KMAX * sizeof(unsigned);
    Acc* accp = (Acc*)(wsb + ((pkBytes + 255) & ~(size_t)255));
    size_t accBytes = (size_t)B * sizeof(Acc);
    float* partial2 = (float*)((char*)accp + ((accBytes + 255) & ~(size_t)255));
    size_t p2Bytes = (size_t)B * nb2 * sizeof(float);
    Ctrl* ctrl = (Ctrl*)((char*)partial2 + ((p2Bytes + 255) & ~(size_t)255));

    k_dedup<<<dim3(nb1, B), 256, 0, stream>>>(tgt, pkeys, P, nb1);
    k_merge<<<B, 256, 0, stream>>>(pkeys, accp, ctrl, nb1);
    k_accum<<<dim3(nb2, B), 256, 0, stream>>>(pred, tgt, accp, P, nb2);
    k_main <<<dim3(nb2, B), 256, 0, stream>>>(pred, tgt, accp, partial2, ctrl,
                                              nb, out, P, B, nb2);
}